// Round 6
// baseline (92.059 us; speedup 1.0000x reference)
//
#include <hip/hip_runtime.h>
#include <hip/hip_bf16.h>
#include <math.h>

#define B_ 2
#define C_ 256
#define H_ 64
#define W_ 64
#define L_ 4096
#define HEADS_ 8
#define DH_ 32
#define CG_ 8
#define K_ 7
#define PAD_ 3
#define K2_ 49
#define PW_ 70
#define PPIX_ 4900
#define WS_STR 72                               // LDS row stride in bf16 (144B, 16B-aligned)

typedef short bf16x8 __attribute__((ext_vector_type(8)));
typedef float f32x4  __attribute__((ext_vector_type(4)));

__device__ inline unsigned short f2bf(float f) {
    union { float f; unsigned u; } uf; uf.f = f;
    unsigned r = uf.u + 0x7fffu + ((uf.u >> 16) & 1u);   // RNE
    return (unsigned short)(r >> 16);
}
__device__ inline unsigned pk2(float a, float b) {
    return (unsigned)f2bf(a) | ((unsigned)f2bf(b) << 16);
}

// ---------------- Kernel 1: QKV projection via bf16 MFMA -------------------
// D[o][l] = sum_c W[o][c] * X[c][l].  Block: all 256 o x 64 l (one image row).
// Weights converted f32->bf16 inline during staging. K/V halo zeroed here too.
__global__ __launch_bounds__(256) void qkv_mfma(
    const float* __restrict__ q_in, const float* __restrict__ k_in, const float* __restrict__ v_in,
    const float* __restrict__ wq, const float* __restrict__ wk, const float* __restrict__ wv,
    const float* __restrict__ bq, const float* __restrict__ bk, const float* __restrict__ bv,
    float4* __restrict__ qt4, float4* __restrict__ kt4, float4* __restrict__ vt4)
{
    const int z = blockIdx.z;
    const int which = z >> 1;      // 0=q,1=k,2=v
    const int b = z & 1;
    const float* X    = (which==0) ? q_in : (which==1 ? k_in : v_in);
    const float* wsrc = (which==0) ? wq   : (which==1 ? wk   : wv);
    const float* bias = (which==0) ? bq   : (which==1 ? bk   : bv);

    const int y  = blockIdx.x;        // image row
    const int l0 = y * 64;
    const int tid = threadIdx.x;
    const int lane = tid & 63, wave = tid >> 6;
    const int orow = lane & 15, kgrp = lane >> 4;

    __shared__ short Ws[256*WS_STR];   // weights [o][c-chunk] bf16
    __shared__ short Xs[64*WS_STR];    // input^T [l][c-chunk] bf16

    // ---- halo zeroing for K/V (independent of GEMM; no sync needed) ----
    if (which != 0) {
        float4* dst = (which==1) ? kt4 : vt4;
        const float4 zz = make_float4(0.f,0.f,0.f,0.f);
        // edge cells of this row's padded row (y+3): x in {0,1,2,67,68,69}, 64 planes
        for (int e = tid; e < 384; e += 256) {
            int pl = e / 6, j = e - pl*6;
            int xx = (j < 3) ? j : (64 + j);
            dst[(size_t)(b*64 + pl)*PPIX_ + (size_t)(y+PAD_)*PW_ + xx] = zz;
        }
        // top 3 / bottom 3 full padded rows
        int hrow = (y < 3) ? y : ((y >= 61) ? (y + 6) : -1);
        if (hrow >= 0) {
            for (int e = tid; e < 64*PW_; e += 256) {
                int pl = e / PW_, xx = e - pl*PW_;
                dst[(size_t)(b*64 + pl)*PPIX_ + (size_t)hrow*PW_ + xx] = zz;
            }
        }
    }

    f32x4 acc[4][4] = {};
    const int cq  = tid >> 6;   // 0..3
    const int lst = tid & 63;

    for (int ch = 0; ch < 4; ++ch) {
        const int c0 = ch*64;
        // stage Ws: 256 o x 64 c, f32 -> bf16 inline (float4 = 4 c per thread)
        #pragma unroll
        for (int i = 0; i < 16; ++i) {
            int o  = i*16 + (tid>>4);
            int c4 = tid & 15;
            float4 wv4 = *reinterpret_cast<const float4*>(&wsrc[(size_t)o*C_ + c0 + c4*4]);
            uint2 pk; pk.x = pk2(wv4.x, wv4.y); pk.y = pk2(wv4.z, wv4.w);
            *reinterpret_cast<uint2*>(&Ws[o*WS_STR + c4*4]) = pk;
        }
        // stage Xs: 64 l x 64 c, f32 -> bf16 with transpose (coalesced reads)
        #pragma unroll
        for (int i = 0; i < 8; ++i) {
            int cc = cq*2 + i*8;
            float a  = X[(size_t)(b*C_ + c0 + cc    )*L_ + l0 + lst];
            float b2 = X[(size_t)(b*C_ + c0 + cc + 1)*L_ + l0 + lst];
            *reinterpret_cast<unsigned*>(&Xs[lst*WS_STR + cc]) = pk2(a, b2);
        }
        __syncthreads();
        #pragma unroll
        for (int kk = 0; kk < 2; ++kk) {
            bf16x8 af[4], bfr[4];
            #pragma unroll
            for (int fo = 0; fo < 4; ++fo)
                af[fo] = *reinterpret_cast<const bf16x8*>(&Ws[(wave*64 + fo*16 + orow)*WS_STR + kk*32 + kgrp*8]);
            #pragma unroll
            for (int fn = 0; fn < 4; ++fn)
                bfr[fn] = *reinterpret_cast<const bf16x8*>(&Xs[(fn*16 + orow)*WS_STR + kk*32 + kgrp*8]);
            #pragma unroll
            for (int fo = 0; fo < 4; ++fo)
                #pragma unroll
                for (int fn = 0; fn < 4; ++fn)
                    acc[fo][fn] = __builtin_amdgcn_mfma_f32_16x16x32_bf16(af[fo], bfr[fn], acc[fo][fn], 0, 0, 0);
        }
        __syncthreads();
    }

    #pragma unroll
    for (int fo = 0; fo < 4; ++fo) {
        const int o_base = wave*64 + fo*16 + kgrp*4;
        const float4 b4 = *reinterpret_cast<const float4*>(&bias[o_base]);
        const size_t p = (size_t)(b*64 + (o_base >> 2));   // plane index
        #pragma unroll
        for (int fn = 0; fn < 4; ++fn) {
            const int xl = fn*16 + orow;
            float4 r;
            r.x = acc[fo][fn][0] + b4.x;
            r.y = acc[fo][fn][1] + b4.y;
            r.z = acc[fo][fn][2] + b4.z;
            r.w = acc[fo][fn][3] + b4.w;
            if (which == 0) {
                qt4[p*L_ + l0 + xl] = r;
            } else {
                float4* dst = (which==1) ? kt4 : vt4;
                dst[p*PPIX_ + (size_t)(y+PAD_)*PW_ + (xl+PAD_)] = r;
            }
        }
    }
}

// ---------------- Kernel 2: 7x7 local attention, 8-wave pixel-team --------
// Block = (plane = b*8+h, row-pair y0,y0+1), 512 threads.
// team t = wave>>2 -> pixel y0+t;  sub s = wave&3.
// QK: sub s covers window-row offsets {2s, 2s+1} ∩ [0,6] for its pixel (full
//     channel sum, logits -> LDS). Softmax duplicated per wave (p[49] regs).
// PV: sub s covers channel-groups {2s, 2s+1} for its pixel. Output over Q.
__global__ __launch_bounds__(512) void local_attn(
    float4* __restrict__ qt4, const float4* __restrict__ kt4, const float4* __restrict__ vt4)
{
    const int tid = threadIdx.x;
    const int w = tid >> 6, x = tid & 63;
    const int t = w >> 2;            // pixel team
    const int s = w & 3;             // sub-wave
    const int bid = blockIdx.x;
    const int plane = bid & 15;      // b*HEADS_+h (all row-pairs of a plane on one XCD slot)
    const int y0 = (bid >> 4) * 2;
    const int py = y0 + t;           // my pixel's image row

    const float4* kb = kt4 + (size_t)plane*CG_*PPIX_;
    const float4* vb = vt4 + (size_t)plane*CG_*PPIX_;
    float4* qpl = qt4 + (size_t)plane*CG_*L_;

    __shared__ float S[2][K2_][64];

    // Q for my pixel, all channel groups
    float4 q[CG_];
    #pragma unroll
    for (int cg=0; cg<CG_; ++cg) q[cg] = qpl[(size_t)cg*L_ + py*W_ + x];

    // ---- QK: my window-row offsets (pixel py attends padded rows py..py+6) ----
    float lg[2][K_];
    #pragma unroll
    for (int oo=0; oo<2; ++oo)
        #pragma unroll
        for (int kx=0; kx<K_; ++kx) lg[oo][kx] = 0.f;

    #pragma unroll
    for (int cg=0; cg<CG_; ++cg) {
        const float4 qc = q[cg];
        #pragma unroll
        for (int oo=0; oo<2; ++oo) {
            const int o = s*2 + oo;
            if (o > 6) continue;                       // wave-uniform
            const float4* row = kb + (size_t)cg*PPIX_ + (size_t)(py + o)*PW_ + x;
            #pragma unroll
            for (int kx=0; kx<K_; ++kx) {
                float4 kv = row[kx];
                lg[oo][kx] = fmaf(qc.x,kv.x, fmaf(qc.y,kv.y, fmaf(qc.z,kv.z, fmaf(qc.w,kv.w, lg[oo][kx]))));
            }
        }
    }
    #pragma unroll
    for (int oo=0; oo<2; ++oo) {
        const int o = s*2 + oo;
        if (o <= 6) {
            #pragma unroll
            for (int kx=0; kx<K_; ++kx) S[t][o*K_+kx][x] = lg[oo][kx];
        }
    }
    __syncthreads();

    // ---- softmax for my pixel (duplicated across the 4 subs of the team) ----
    float p[K2_];
    #pragma unroll
    for (int i=0;i<K2_;++i) p[i] = S[t][i][x];
    const float scale = 0.0625f; // 1/sqrt(256)
    float m = p[0];
    #pragma unroll
    for (int i=1;i<K2_;++i) m = fmaxf(m, p[i]);
    float sum = 0.f;
    #pragma unroll
    for (int i=0;i<K2_;++i) { p[i] = __expf((p[i]-m)*scale); sum += p[i]; }
    const float inv = 1.0f/sum;

    // ---- PV: my two channel groups, my pixel ----
    #pragma unroll
    for (int ci=0; ci<2; ++ci) {
        const int cg = s*2 + ci;
        float4 a = make_float4(0.f,0.f,0.f,0.f);
        const float4* plv = vb + (size_t)cg*PPIX_;
        #pragma unroll
        for (int o=0; o<K_; ++o) {
            const float4* row = plv + (size_t)(py + o)*PW_ + x;
            #pragma unroll
            for (int kx=0; kx<K_; ++kx) {
                float4 vv = row[kx];
                float pp = p[o*K_+kx];
                a.x = fmaf(pp, vv.x, a.x); a.y = fmaf(pp, vv.y, a.y);
                a.z = fmaf(pp, vv.z, a.z); a.w = fmaf(pp, vv.w, a.w);
            }
        }
        a.x *= inv; a.y *= inv; a.z *= inv; a.w *= inv;
        qpl[(size_t)cg*L_ + py*W_ + x] = a;   // safe: each cell read only pre-barrier by this block
    }
}

// ---------------- Kernel 3: output projection via bf16 MFMA ----------------
__global__ __launch_bounds__(256) void out_mfma(
    const float4* __restrict__ qt4, const float* __restrict__ wo,
    const float* __restrict__ bo, float* __restrict__ out)
{
    const int b  = blockIdx.z;
    const int l0 = blockIdx.x * 64;
    const int o_t0 = blockIdx.y * 128;
    const int tid = threadIdx.x;
    const int lane = tid & 63, wave = tid >> 6;
    const int orow = lane & 15, kgrp = lane >> 4;

    __shared__ short Ws[128*WS_STR];
    __shared__ short Xs[64*WS_STR];

    f32x4 acc[2][4] = {};
    const int cq  = tid >> 6;
    const int lst = tid & 63;

    for (int ch = 0; ch < 4; ++ch) {
        const int c0 = ch*64;
        #pragma unroll
        for (int i = 0; i < 8; ++i) {
            int o  = i*16 + (tid>>4);
            int c4 = tid & 15;
            float4 wv4 = *reinterpret_cast<const float4*>(&wo[(size_t)(o_t0 + o)*C_ + c0 + c4*4]);
            uint2 pk; pk.x = pk2(wv4.x, wv4.y); pk.y = pk2(wv4.z, wv4.w);
            *reinterpret_cast<uint2*>(&Ws[o*WS_STR + c4*4]) = pk;
        }
        #pragma unroll
        for (int i = 0; i < 4; ++i) {
            int c4i = i*4 + cq;
            float4 vv = qt4[(size_t)(b*64 + (c0>>2) + c4i)*L_ + l0 + lst];
            *reinterpret_cast<unsigned*>(&Xs[lst*WS_STR + c4i*4    ]) = pk2(vv.x, vv.y);
            *reinterpret_cast<unsigned*>(&Xs[lst*WS_STR + c4i*4 + 2]) = pk2(vv.z, vv.w);
        }
        __syncthreads();
        #pragma unroll
        for (int kk = 0; kk < 2; ++kk) {
            bf16x8 af[2], bfr[4];
            #pragma unroll
            for (int fo = 0; fo < 2; ++fo)
                af[fo] = *reinterpret_cast<const bf16x8*>(&Ws[(wave*32 + fo*16 + orow)*WS_STR + kk*32 + kgrp*8]);
            #pragma unroll
            for (int fn = 0; fn < 4; ++fn)
                bfr[fn] = *reinterpret_cast<const bf16x8*>(&Xs[(fn*16 + orow)*WS_STR + kk*32 + kgrp*8]);
            #pragma unroll
            for (int fo = 0; fo < 2; ++fo)
                #pragma unroll
                for (int fn = 0; fn < 4; ++fn)
                    acc[fo][fn] = __builtin_amdgcn_mfma_f32_16x16x32_bf16(af[fo], bfr[fn], acc[fo][fn], 0, 0, 0);
        }
        __syncthreads();
    }

    #pragma unroll
    for (int fo = 0; fo < 2; ++fo) {
        const int o_base = o_t0 + wave*32 + fo*16 + kgrp*4;
        #pragma unroll
        for (int fn = 0; fn < 4; ++fn) {
            const int xl = fn*16 + orow;
            #pragma unroll
            for (int r = 0; r < 4; ++r)
                out[(size_t)(b*C_ + o_base + r)*L_ + l0 + xl] = acc[fo][fn][r] + bo[o_base + r];
        }
    }
}

extern "C" void kernel_launch(void* const* d_in, const int* in_sizes, int n_in,
                              void* d_out, int out_size, void* d_ws, size_t ws_size,
                              hipStream_t stream) {
    const float* queries = (const float*)d_in[0];
    const float* keys    = (const float*)d_in[1];
    const float* values  = (const float*)d_in[2];
    const float* wq = (const float*)d_in[3];
    const float* bq = (const float*)d_in[4];
    const float* wk = (const float*)d_in[5];
    const float* bk = (const float*)d_in[6];
    const float* wv = (const float*)d_in[7];
    const float* bv = (const float*)d_in[8];
    const float* wo = (const float*)d_in[9];
    const float* bo = (const float*)d_in[10];
    float* out = (float*)d_out;

    const size_t PADT4 = (size_t)B_*HEADS_*CG_*PPIX_;      // 627200 float4
    float4* qt4 = (float4*)d_ws;                           // Q planar-c4, attn out in-place
    float4* kt4 = qt4 + (size_t)B_*HEADS_*CG_*L_;          // padded planar K
    float4* vt4 = kt4 + PADT4;                             // padded planar V

    qkv_mfma<<<dim3(64, 1, 6), 256, 0, stream>>>(queries, keys, values,
                                                 wq, wk, wv, bq, bk, bv, qt4, kt4, vt4);
    local_attn<<<512, 512, 0, stream>>>(qt4, kt4, vt4);
    out_mfma<<<dim3(64, 2, 2), 256, 0, stream>>>(qt4, wo, bo, out);
}

// Round 7
// 75.283 us; speedup vs baseline: 1.2228x; 1.2228x over previous
//
#include <hip/hip_runtime.h>
#include <hip/hip_bf16.h>
#include <math.h>

#define B_ 2
#define C_ 256
#define H_ 64
#define W_ 64
#define L_ 4096
#define HEADS_ 8
#define DH_ 32
#define CG_ 8
#define K_ 7
#define PAD_ 3
#define K2_ 49
#define PW_ 70
#define PPIX_ 4900
#define PADT4_ ((size_t)B_*HEADS_*CG_*PPIX_)   // 627200 float4 per padded tensor
#define WS_STR 72                               // LDS row stride in bf16 (144B, 16B-aligned)

typedef short bf16x8 __attribute__((ext_vector_type(8)));
typedef float f32x4  __attribute__((ext_vector_type(4)));

__device__ inline unsigned short f2bf(float f) {
    union { float f; unsigned u; } uf; uf.f = f;
    unsigned r = uf.u + 0x7fffu + ((uf.u >> 16) & 1u);   // RNE
    return (unsigned short)(r >> 16);
}
__device__ inline unsigned pk2(float a, float b) {
    return (unsigned)f2bf(a) | ((unsigned)f2bf(b) << 16);
}

// ---------------- Kernel A: pack 4 weight matrices to bf16 (u32 pairs) ------
__global__ __launch_bounds__(256) void wconv(
    const float* __restrict__ wq, const float* __restrict__ wk,
    const float* __restrict__ wv, const float* __restrict__ wo,
    unsigned* __restrict__ wb)
{
    int idx = blockIdx.x*256 + threadIdx.x;   // 0..131071
    const float* src = (idx < 32768) ? wq : (idx < 65536) ? wk : (idx < 98304) ? wv : wo;
    int off = (idx & 32767) * 2;
    float a = src[off], b = src[off+1];
    wb[idx] = pk2(a, b);
}

// ---------------- Kernel B: zero the padded halo of K/V ----------------
__global__ __launch_bounds__(256) void halo_zero(float4* __restrict__ kt, float4* __restrict__ vt)
{
    int idx = blockIdx.x*256 + threadIdx.x;
    if (idx >= (int)PADT4_) return;
    int cell = idx % PPIX_;
    int px = cell % PW_, py = cell / PW_;
    if (px < PAD_ || px >= PW_-PAD_ || py < PAD_ || py >= PW_-PAD_) {
        float4 z = make_float4(0.f,0.f,0.f,0.f);
        kt[idx] = z;
        vt[idx] = z;
    }
}

// ---------------- Kernel C: QKV projection via bf16 MFMA (prepacked W) -----
__global__ __launch_bounds__(256) void qkv_mfma(
    const float* __restrict__ q_in, const float* __restrict__ k_in, const float* __restrict__ v_in,
    const unsigned* __restrict__ wb,
    const float* __restrict__ bq, const float* __restrict__ bk, const float* __restrict__ bv,
    float4* __restrict__ qt4, float4* __restrict__ kt4, float4* __restrict__ vt4)
{
    const int z = blockIdx.z;
    const int which = z >> 1;      // 0=q,1=k,2=v
    const int b = z & 1;
    const float* X = (which==0) ? q_in : (which==1 ? k_in : v_in);
    const unsigned* wbp = wb + which*32768;
    const float* bias = (which==0) ? bq : (which==1 ? bk : bv);

    const int y  = blockIdx.x;
    const int l0 = y * 64;
    const int tid = threadIdx.x;
    const int lane = tid & 63, wave = tid >> 6;
    const int orow = lane & 15, kgrp = lane >> 4;

    __shared__ short Ws[256*WS_STR];   // weights [o][c-chunk]
    __shared__ short Xs[64*WS_STR];    // input^T [l][c-chunk]

    f32x4 acc[4][4] = {};
    const int cq  = tid >> 6;
    const int lst = tid & 63;

    for (int ch = 0; ch < 4; ++ch) {
        const int c0 = ch*64;
        #pragma unroll
        for (int i = 0; i < 16; ++i) {
            int o  = i*16 + (tid>>4);
            int c4 = tid & 15;
            uint2 v = *reinterpret_cast<const uint2*>(wbp + o*128 + (c0>>1) + c4*2);
            *reinterpret_cast<uint2*>(&Ws[o*WS_STR + c4*4]) = v;
        }
        #pragma unroll
        for (int i = 0; i < 8; ++i) {
            int cc = cq*2 + i*8;
            float a  = X[(size_t)(b*C_ + c0 + cc    )*L_ + l0 + lst];
            float b2 = X[(size_t)(b*C_ + c0 + cc + 1)*L_ + l0 + lst];
            *reinterpret_cast<unsigned*>(&Xs[lst*WS_STR + cc]) = pk2(a, b2);
        }
        __syncthreads();
        #pragma unroll
        for (int kk = 0; kk < 2; ++kk) {
            bf16x8 af[4], bfr[4];
            #pragma unroll
            for (int fo = 0; fo < 4; ++fo)
                af[fo] = *reinterpret_cast<const bf16x8*>(&Ws[(wave*64 + fo*16 + orow)*WS_STR + kk*32 + kgrp*8]);
            #pragma unroll
            for (int fn = 0; fn < 4; ++fn)
                bfr[fn] = *reinterpret_cast<const bf16x8*>(&Xs[(fn*16 + orow)*WS_STR + kk*32 + kgrp*8]);
            #pragma unroll
            for (int fo = 0; fo < 4; ++fo)
                #pragma unroll
                for (int fn = 0; fn < 4; ++fn)
                    acc[fo][fn] = __builtin_amdgcn_mfma_f32_16x16x32_bf16(af[fo], bfr[fn], acc[fo][fn], 0, 0, 0);
        }
        __syncthreads();
    }

    #pragma unroll
    for (int fo = 0; fo < 4; ++fo) {
        const int o_base = wave*64 + fo*16 + kgrp*4;
        const float4 b4 = *reinterpret_cast<const float4*>(&bias[o_base]);
        const size_t p = (size_t)(b*64 + (o_base >> 2));
        #pragma unroll
        for (int fn = 0; fn < 4; ++fn) {
            const int xl = fn*16 + orow;
            float4 r;
            r.x = acc[fo][fn][0] + b4.x;
            r.y = acc[fo][fn][1] + b4.y;
            r.z = acc[fo][fn][2] + b4.z;
            r.w = acc[fo][fn][3] + b4.w;
            if (which == 0) {
                qt4[p*L_ + l0 + xl] = r;
            } else {
                float4* dst = (which==1) ? kt4 : vt4;
                dst[p*PPIX_ + (size_t)(y+PAD_)*PW_ + (xl+PAD_)] = r;
            }
        }
    }
}

// ---------------- Kernel D: 7x7 local attention, LDS-staged bf16 K/V -------
// Block = (plane, row-pair), 4 waves. K staged bf16 in LDS -> QK (wave: 2 window
// rows, both pixels); logits via LDS; V staged over same buffer; PV (wave: 2 cg).
__global__ __launch_bounds__(256) void local_attn(
    float4* __restrict__ qt4, const float4* __restrict__ kt4, const float4* __restrict__ vt4)
{
    const int tid = threadIdx.x;
    const int w = tid >> 6, x = tid & 63;
    const int bid = blockIdx.x;
    const int plane = bid & 15;
    const int y0 = (bid >> 4) * 2;

    const float4* kb = kt4 + (size_t)plane*CG_*PPIX_;
    const float4* vb = vt4 + (size_t)plane*CG_*PPIX_;
    float4* qpl = qt4 + (size_t)plane*CG_*L_;

    __shared__ uint2 buf[CG_*8*PW_];     // [cg][r][xp], 4 ch bf16 each: 35.8 KB
    __shared__ float S[2][K2_][64];      // logits: 24.5 KB   (total 60.3 KB)

    // Q loads (issued first; overlap K staging latency)
    float4 qa[CG_], qb[CG_];
    #pragma unroll
    for (int cg=0; cg<CG_; ++cg) {
        qa[cg] = qpl[(size_t)cg*L_ + (y0  )*W_ + x];
        qb[cg] = qpl[(size_t)cg*L_ + (y0+1)*W_ + x];
    }

    // ---- stage K as bf16 ----
    #pragma unroll
    for (int i = 0; i < 18; ++i) {
        int e = tid + i*256;
        if (e < CG_*8*PW_) {
            int cg = e / (8*PW_), r = (e / PW_) & 7, xp = e % PW_;
            float4 kv = kb[(size_t)cg*PPIX_ + (size_t)(y0+r)*PW_ + xp];
            buf[e] = make_uint2(pk2(kv.x,kv.y), pk2(kv.z,kv.w));
        }
    }
    __syncthreads();

    // ---- QK: wave w covers window rows {2w, 2w+1}, both pixels ----
    float lgA[2][K_] = {};   // pixel y0   (valid rows r<7)
    float lgB[2][K_] = {};   // pixel y0+1 (valid rows r>0, ky=r-1)
    #pragma unroll
    for (int cg=0; cg<CG_; ++cg) {
        const float4 q0 = qa[cg], q1 = qb[cg];
        #pragma unroll
        for (int rr=0; rr<2; ++rr) {
            const int r = w*2 + rr;
            const uint2* row = &buf[(cg*8 + r)*PW_ + x];
            #pragma unroll
            for (int kx=0; kx<K_; ++kx) {
                uint2 kk = row[kx];
                float k0 = __uint_as_float(kk.x << 16);
                float k1 = __uint_as_float(kk.x & 0xffff0000u);
                float k2 = __uint_as_float(kk.y << 16);
                float k3 = __uint_as_float(kk.y & 0xffff0000u);
                if (r < 7) lgA[rr][kx] = fmaf(q0.x,k0, fmaf(q0.y,k1, fmaf(q0.z,k2, fmaf(q0.w,k3, lgA[rr][kx]))));
                if (r > 0) lgB[rr][kx] = fmaf(q1.x,k0, fmaf(q1.y,k1, fmaf(q1.z,k2, fmaf(q1.w,k3, lgB[rr][kx]))));
            }
        }
    }
    #pragma unroll
    for (int rr=0; rr<2; ++rr) {
        const int r = w*2 + rr;
        if (r < 7) {
            #pragma unroll
            for (int kx=0; kx<K_; ++kx) S[0][r*K_+kx][x] = lgA[rr][kx];
        }
        if (r > 0) {
            #pragma unroll
            for (int kx=0; kx<K_; ++kx) S[1][(r-1)*K_+kx][x] = lgB[rr][kx];
        }
    }
    __syncthreads();   // S complete; all K reads of buf complete

    // ---- stage V over the same buffer (latency overlaps softmax below) ----
    #pragma unroll
    for (int i = 0; i < 18; ++i) {
        int e = tid + i*256;
        if (e < CG_*8*PW_) {
            int cg = e / (8*PW_), r = (e / PW_) & 7, xp = e % PW_;
            float4 vv = vb[(size_t)cg*PPIX_ + (size_t)(y0+r)*PW_ + xp];
            buf[e] = make_uint2(pk2(vv.x,vv.y), pk2(vv.z,vv.w));
        }
    }

    // ---- softmax for both pixels (register-resident) ----
    float p0[K2_], p1[K2_];
    #pragma unroll
    for (int i=0;i<K2_;++i) { p0[i] = S[0][i][x]; p1[i] = S[1][i][x]; }
    const float scale = 0.0625f; // 1/sqrt(256)
    float m0 = p0[0], m1 = p1[0];
    #pragma unroll
    for (int i=1;i<K2_;++i) { m0 = fmaxf(m0, p0[i]); m1 = fmaxf(m1, p1[i]); }
    float s0 = 0.f, s1 = 0.f;
    #pragma unroll
    for (int i=0;i<K2_;++i) {
        p0[i] = __expf((p0[i]-m0)*scale); s0 += p0[i];
        p1[i] = __expf((p1[i]-m1)*scale); s1 += p1[i];
    }
    const float inv0 = 1.0f/s0, inv1 = 1.0f/s1;
    __syncthreads();   // V staged

    // ---- PV: wave w covers channel-groups {2w, 2w+1}, both pixels ----
    #pragma unroll
    for (int ci=0; ci<2; ++ci) {
        const int cg = w*2 + ci;
        float4 a0 = make_float4(0.f,0.f,0.f,0.f);
        float4 a1 = make_float4(0.f,0.f,0.f,0.f);
        #pragma unroll
        for (int r=0; r<8; ++r) {
            const uint2* row = &buf[(cg*8 + r)*PW_ + x];
            #pragma unroll
            for (int kx=0; kx<K_; ++kx) {
                uint2 vk = row[kx];
                float v0 = __uint_as_float(vk.x << 16);
                float v1 = __uint_as_float(vk.x & 0xffff0000u);
                float v2 = __uint_as_float(vk.y << 16);
                float v3 = __uint_as_float(vk.y & 0xffff0000u);
                if (r < 7) {
                    float pp = p0[r*K_+kx];
                    a0.x = fmaf(pp, v0, a0.x); a0.y = fmaf(pp, v1, a0.y);
                    a0.z = fmaf(pp, v2, a0.z); a0.w = fmaf(pp, v3, a0.w);
                }
                if (r > 0) {
                    float pp = p1[(r-1)*K_+kx];
                    a1.x = fmaf(pp, v0, a1.x); a1.y = fmaf(pp, v1, a1.y);
                    a1.z = fmaf(pp, v2, a1.z); a1.w = fmaf(pp, v3, a1.w);
                }
            }
        }
        a0.x *= inv0; a0.y *= inv0; a0.z *= inv0; a0.w *= inv0;
        a1.x *= inv1; a1.y *= inv1; a1.z *= inv1; a1.w *= inv1;
        qpl[(size_t)cg*L_ + (y0  )*W_ + x] = a0;
        qpl[(size_t)cg*L_ + (y0+1)*W_ + x] = a1;
    }
}

// ---------------- Kernel E: output projection via bf16 MFMA (prepacked W) ---
__global__ __launch_bounds__(256) void out_mfma(
    const float4* __restrict__ qt4, const unsigned* __restrict__ wb,
    const float* __restrict__ bo, float* __restrict__ out)
{
    const int b  = blockIdx.z;
    const int l0 = blockIdx.x * 64;
    const int o_t0 = blockIdx.y * 128;
    const unsigned* wbp = wb + 3*32768;
    const int tid = threadIdx.x;
    const int lane = tid & 63, wave = tid >> 6;
    const int orow = lane & 15, kgrp = lane >> 4;

    __shared__ short Ws[128*WS_STR];
    __shared__ short Xs[64*WS_STR];

    f32x4 acc[2][4] = {};
    const int cq  = tid >> 6;
    const int lst = tid & 63;

    for (int ch = 0; ch < 4; ++ch) {
        const int c0 = ch*64;
        #pragma unroll
        for (int i = 0; i < 8; ++i) {
            int o  = i*16 + (tid>>4);
            int c4 = tid & 15;
            uint2 v = *reinterpret_cast<const uint2*>(wbp + (size_t)(o_t0 + o)*128 + (c0>>1) + c4*2);
            *reinterpret_cast<uint2*>(&Ws[o*WS_STR + c4*4]) = v;
        }
        #pragma unroll
        for (int i = 0; i < 4; ++i) {
            int c4i = i*4 + cq;
            float4 vv = qt4[(size_t)(b*64 + (c0>>2) + c4i)*L_ + l0 + lst];
            *reinterpret_cast<unsigned*>(&Xs[lst*WS_STR + c4i*4    ]) = pk2(vv.x, vv.y);
            *reinterpret_cast<unsigned*>(&Xs[lst*WS_STR + c4i*4 + 2]) = pk2(vv.z, vv.w);
        }
        __syncthreads();
        #pragma unroll
        for (int kk = 0; kk < 2; ++kk) {
            bf16x8 af[2], bfr[4];
            #pragma unroll
            for (int fo = 0; fo < 2; ++fo)
                af[fo] = *reinterpret_cast<const bf16x8*>(&Ws[(wave*32 + fo*16 + orow)*WS_STR + kk*32 + kgrp*8]);
            #pragma unroll
            for (int fn = 0; fn < 4; ++fn)
                bfr[fn] = *reinterpret_cast<const bf16x8*>(&Xs[(fn*16 + orow)*WS_STR + kk*32 + kgrp*8]);
            #pragma unroll
            for (int fo = 0; fo < 2; ++fo)
                #pragma unroll
                for (int fn = 0; fn < 4; ++fn)
                    acc[fo][fn] = __builtin_amdgcn_mfma_f32_16x16x32_bf16(af[fo], bfr[fn], acc[fo][fn], 0, 0, 0);
        }
        __syncthreads();
    }

    #pragma unroll
    for (int fo = 0; fo < 2; ++fo) {
        const int o_base = o_t0 + wave*32 + fo*16 + kgrp*4;
        #pragma unroll
        for (int fn = 0; fn < 4; ++fn) {
            const int xl = fn*16 + orow;
            #pragma unroll
            for (int r = 0; r < 4; ++r)
                out[(size_t)(b*C_ + o_base + r)*L_ + l0 + xl] = acc[fo][fn][r] + bo[o_base + r];
        }
    }
}

extern "C" void kernel_launch(void* const* d_in, const int* in_sizes, int n_in,
                              void* d_out, int out_size, void* d_ws, size_t ws_size,
                              hipStream_t stream) {
    const float* queries = (const float*)d_in[0];
    const float* keys    = (const float*)d_in[1];
    const float* values  = (const float*)d_in[2];
    const float* wq = (const float*)d_in[3];
    const float* bq = (const float*)d_in[4];
    const float* wk = (const float*)d_in[5];
    const float* bk = (const float*)d_in[6];
    const float* wv = (const float*)d_in[7];
    const float* bv = (const float*)d_in[8];
    const float* wo = (const float*)d_in[9];
    const float* bo = (const float*)d_in[10];
    float* out = (float*)d_out;

    float4* qt4 = (float4*)d_ws;                           // Q planar-c4, attn out in-place
    float4* kt4 = qt4 + (size_t)B_*HEADS_*CG_*L_;          // padded planar K
    float4* vt4 = kt4 + PADT4_;                            // padded planar V
    unsigned* wb = (unsigned*)(vt4 + PADT4_);              // bf16 packed weights

    wconv<<<512, 256, 0, stream>>>(wq, wk, wv, wo, wb);
    halo_zero<<<dim3((unsigned)((PADT4_ + 255)/256)), 256, 0, stream>>>(kt4, vt4);
    qkv_mfma<<<dim3(64, 1, 6), 256, 0, stream>>>(queries, keys, values, wb, bq, bk, bv, qt4, kt4, vt4);
    local_attn<<<512, 256, 0, stream>>>(qt4, kt4, vt4);
    out_mfma<<<dim3(64, 2, 2), 256, 0, stream>>>(qt4, wb, bo, out);
}